// Round 2
// baseline (403.801 us; speedup 1.0000x reference)
//
#include <hip/hip_runtime.h>
#include <math.h>

// Problem sizes (fixed by reference setup_inputs)
constexpr int B = 64;
constexpr int S = 1024;
constexpr int H = 1024;
constexpr int L = 3;
#define NEPS 1e-12f

__device__ __forceinline__ float wave_reduce_sum(float v) {
    #pragma unroll
    for (int off = 32; off > 0; off >>= 1) v += __shfl_xor(v, off);
    return v;
}
__device__ __forceinline__ float wave_reduce_max(float v) {
    #pragma unroll
    for (int off = 32; off > 0; off >>= 1) v = fmaxf(v, __shfl_xor(v, off));
    return v;
}

// ---------------------------------------------------------------------------
// Kernel 1: normalize label embeddings over H (dim 0), store transposed
// leT[l][h] = le[h][l] / max(||le[:,l]||, eps).  One block.
// ---------------------------------------------------------------------------
__global__ __launch_bounds__(256) void norm_labels(const float* __restrict__ le,
                                                   float* __restrict__ leT) {
    __shared__ float red[L][4];
    __shared__ float rn[L];
    const int tid = threadIdx.x;
    const int wid = tid >> 6, lane = tid & 63;

    float acc[L] = {0.f, 0.f, 0.f};
    for (int h = tid; h < H; h += 256) {
        #pragma unroll
        for (int l = 0; l < L; ++l) {
            float v = le[h * L + l];
            acc[l] += v * v;
        }
    }
    #pragma unroll
    for (int l = 0; l < L; ++l) {
        float s = wave_reduce_sum(acc[l]);
        if (lane == 0) red[l][wid] = s;
    }
    __syncthreads();
    if (tid < L) {
        float s = red[tid][0] + red[tid][1] + red[tid][2] + red[tid][3];
        rn[tid] = 1.0f / fmaxf(sqrtf(s), NEPS);
    }
    __syncthreads();
    for (int h = tid; h < H; h += 256) {
        #pragma unroll
        for (int l = 0; l < L; ++l)
            leT[l * H + h] = le[h * L + l] * rn[l];
    }
}

// ---------------------------------------------------------------------------
// Kernel 2: one WAVE per (b,s) row (4 rows per block, no LDS, no barriers).
// Lane reads 4 float4s of the row (4 KiB/row total), computes sum(x^2) and
// 3 dots vs normalized labels, 64-lane butterfly reduce, lane 0 writes
// atten[row][l] = dot_l/max(||x||,eps) + bias  and  pooled[row] = max_l.
// ---------------------------------------------------------------------------
__global__ __launch_bounds__(256) void row_kernel(const float* __restrict__ df,
                                                  const float* __restrict__ leT,
                                                  const float* __restrict__ mask,
                                                  float* __restrict__ atten,
                                                  float* __restrict__ pooled) {
    const int wid = threadIdx.x >> 6, lane = threadIdx.x & 63;
    const int row = blockIdx.x * 4 + wid;     // b*S + s
    const float* r = df + (size_t)row * H;

    float ssq = 0.f, d0 = 0.f, d1 = 0.f, d2 = 0.f;
    #pragma unroll
    for (int k = 0; k < 4; ++k) {
        const int idx = (k * 64 + lane) * 4;
        const float4 d  = *(const float4*)(r + idx);
        const float4 a0 = *(const float4*)(leT + 0 * H + idx);
        const float4 a1 = *(const float4*)(leT + 1 * H + idx);
        const float4 a2 = *(const float4*)(leT + 2 * H + idx);
        ssq += d.x * d.x  + d.y * d.y  + d.z * d.z  + d.w * d.w;
        d0  += d.x * a0.x + d.y * a0.y + d.z * a0.z + d.w * a0.w;
        d1  += d.x * a1.x + d.y * a1.y + d.z * a1.z + d.w * a1.w;
        d2  += d.x * a2.x + d.y * a2.y + d.z * a2.z + d.w * a2.w;
    }
    #pragma unroll
    for (int off = 32; off > 0; off >>= 1) {
        ssq += __shfl_xor(ssq, off);
        d0  += __shfl_xor(d0, off);
        d1  += __shfl_xor(d1, off);
        d2  += __shfl_xor(d2, off);
    }
    if (lane == 0) {
        const float rnrm = 1.0f / fmaxf(sqrtf(ssq), NEPS);
        const float bias = 10000.0f * (mask[row] - 1.0f);
        const float v0 = d0 * rnrm + bias;
        const float v1 = d1 * rnrm + bias;
        const float v2 = d2 * rnrm + bias;
        float* o = atten + (size_t)row * L;
        o[0] = v0; o[1] = v1; o[2] = v2;
        pooled[row] = fmaxf(fmaxf(v0, v1), v2);
    }
}

// ---------------------------------------------------------------------------
// Kernel 3: per batch b — softmax over S of pooled (coalesced float4 reads),
// write normalized; also zero feature_attention[b][:] for kernel 4's atomics.
// ---------------------------------------------------------------------------
__global__ __launch_bounds__(256) void softmax_kernel(const float* __restrict__ pooled,
                                                      float* __restrict__ norm,
                                                      float* __restrict__ fa) {
    const int b = blockIdx.x;
    const int tid = threadIdx.x;
    const int wid = tid >> 6, lane = tid & 63;

    // zero the atomic accumulation target (stream-ordered before kernel 4)
    *(float4*)(fa + (size_t)b * H + tid * 4) = make_float4(0.f, 0.f, 0.f, 0.f);

    const float4 p = *(const float4*)(pooled + (size_t)b * S + tid * 4);

    __shared__ float redm[4];
    __shared__ float reds[4];
    float m = fmaxf(fmaxf(p.x, p.y), fmaxf(p.z, p.w));
    m = wave_reduce_max(m);
    if (lane == 0) redm[wid] = m;
    __syncthreads();
    m = fmaxf(fmaxf(redm[0], redm[1]), fmaxf(redm[2], redm[3]));

    float4 e;
    e.x = expf(p.x - m);
    e.y = expf(p.y - m);
    e.z = expf(p.z - m);
    e.w = expf(p.w - m);
    float ssum = e.x + e.y + e.z + e.w;
    ssum = wave_reduce_sum(ssum);
    if (lane == 0) reds[wid] = ssum;
    __syncthreads();
    const float rs = 1.0f / (reds[0] + reds[1] + reds[2] + reds[3]);

    e.x *= rs; e.y *= rs; e.z *= rs; e.w *= rs;
    *(float4*)(norm + (size_t)b * S + tid * 4) = e;
}

// ---------------------------------------------------------------------------
// Kernel 4: feature_attention[b][h] = sum_s norm[b][s] * df[b][s][h].
// Grid (S/SCHUNK, B) = (32, 64) -> 2048 blocks (8/CU).  Each block streams
// 32 contiguous rows (128 KiB), accumulates in registers, atomicAdds once.
// ---------------------------------------------------------------------------
constexpr int SCHUNK = 32;
__global__ __launch_bounds__(256) void weighted_sum(const float* __restrict__ df,
                                                    const float* __restrict__ norm,
                                                    float* __restrict__ fa) {
    const int c = blockIdx.x;   // s chunk
    const int b = blockIdx.y;
    const int tid = threadIdx.x;

    __shared__ float w[SCHUNK];
    if (tid < SCHUNK) w[tid] = norm[(size_t)b * S + c * SCHUNK + tid];
    __syncthreads();

    const float* base = df + ((size_t)b * S + (size_t)c * SCHUNK) * H + tid * 4;
    float4 acc = make_float4(0.f, 0.f, 0.f, 0.f);
    #pragma unroll 8
    for (int i = 0; i < SCHUNK; ++i) {
        const float4 d = *(const float4*)(base + (size_t)i * H);
        const float ww = w[i];
        acc.x += ww * d.x;
        acc.y += ww * d.y;
        acc.z += ww * d.z;
        acc.w += ww * d.w;
    }
    float* o = fa + (size_t)b * H + tid * 4;
    atomicAdd(o + 0, acc.x);
    atomicAdd(o + 1, acc.y);
    atomicAdd(o + 2, acc.z);
    atomicAdd(o + 3, acc.w);
}

// ---------------------------------------------------------------------------
extern "C" void kernel_launch(void* const* d_in, const int* in_sizes, int n_in,
                              void* d_out, int out_size, void* d_ws, size_t ws_size,
                              hipStream_t stream) {
    const float* df   = (const float*)d_in[0];  // [B,S,H]
    const float* le   = (const float*)d_in[1];  // [H,L]
    const float* mask = (const float*)d_in[2];  // [B,S]

    float* out   = (float*)d_out;
    float* fa    = out;                          // [B,H]        65536
    float* atten = out + (size_t)B * H;          // [B,S,L]      196608
    float* norm  = atten + (size_t)B * S * L;    // [B,1,S]      65536

    float* leT    = (float*)d_ws;                // [L,H]   12288 floats
    float* pooled = leT + (size_t)L * H;         // [B,S]   65536 floats

    norm_labels<<<1, 256, 0, stream>>>(le, leT);
    row_kernel<<<(B * S) / 4, 256, 0, stream>>>(df, leT, mask, atten, pooled);
    softmax_kernel<<<B, 256, 0, stream>>>(pooled, norm, fa);
    weighted_sum<<<dim3(S / SCHUNK, B), 256, 0, stream>>>(df, norm, fa);
}

// Round 5
// 370.113 us; speedup vs baseline: 1.0910x; 1.0910x over previous
//
#include <hip/hip_runtime.h>
#include <math.h>

// Problem sizes (fixed by reference setup_inputs)
constexpr int B = 64;
constexpr int S = 1024;
constexpr int H = 1024;
constexpr int L = 3;
constexpr int WPB = 64;            // waves (partials) per batch
constexpr int RPW = S / WPB;       // rows per wave = 16
#define NEPS 1e-12f

__device__ __forceinline__ float wave_reduce_sum(float v) {
    #pragma unroll
    for (int off = 32; off > 0; off >>= 1) v += __shfl_xor(v, off);
    return v;
}
__device__ __forceinline__ float wave_reduce_max(float v) {
    #pragma unroll
    for (int off = 32; off > 0; off >>= 1) v = fmaxf(v, __shfl_xor(v, off));
    return v;
}

// ---------------------------------------------------------------------------
// Kernel 1: normalize label embeddings over H (dim 0), store transposed
// leT[l][h] = le[h][l] / max(||le[:,l]||, eps).  One block.
// ---------------------------------------------------------------------------
__global__ __launch_bounds__(256) void norm_labels(const float* __restrict__ le,
                                                   float* __restrict__ leT) {
    __shared__ float red[L][4];
    __shared__ float rn[L];
    const int tid = threadIdx.x;
    const int wid = tid >> 6, lane = tid & 63;

    float acc[L] = {0.f, 0.f, 0.f};
    for (int h = tid; h < H; h += 256) {
        #pragma unroll
        for (int l = 0; l < L; ++l) {
            float v = le[h * L + l];
            acc[l] += v * v;
        }
    }
    #pragma unroll
    for (int l = 0; l < L; ++l) {
        float s = wave_reduce_sum(acc[l]);
        if (lane == 0) red[l][wid] = s;
    }
    __syncthreads();
    if (tid < L) {
        float s = red[tid][0] + red[tid][1] + red[tid][2] + red[tid][3];
        rn[tid] = 1.0f / fmaxf(sqrtf(s), NEPS);
    }
    __syncthreads();
    for (int h = tid; h < H; h += 256) {
        #pragma unroll
        for (int l = 0; l < L; ++l)
            leT[l * H + h] = le[h * L + l] * rn[l];
    }
}

// ---------------------------------------------------------------------------
// Kernel 2 (fused stream): each WAVE owns RPW=16 consecutive rows of one
// batch.  Per row: load the 4 KiB row into registers (4x float4/lane,
// interleaved layout h = (k*64+lane)*4+c), compute sum(x^2) + 3 dots vs
// label fragments held in registers, butterfly-reduce, emit atten+pooled,
// and accumulate acc += e^(p-m) * row with online max/sum rescaling.
// df is read ONCE for the whole problem.  Wave partials (m, Z, acc[H]) go
// to workspace for the epilogue.
// ---------------------------------------------------------------------------
__global__ __launch_bounds__(256) void fused_stream(const float* __restrict__ df,
                                                    const float* __restrict__ leT,
                                                    const float* __restrict__ mask,
                                                    float* __restrict__ atten,
                                                    float* __restrict__ pooled,
                                                    float* __restrict__ accp,
                                                    float* __restrict__ mz) {
    const int wid = threadIdx.x >> 6, lane = threadIdx.x & 63;
    const int gw = blockIdx.x * 4 + wid;      // global wave id 0..4095
    const int b = gw / WPB;
    const int j = gw % WPB;                   // partial slot within batch
    const int s0 = j * RPW;

    // label fragments in registers (same interleaved layout as row loads)
    float4 L0[4], L1[4], L2[4];
    #pragma unroll
    for (int k = 0; k < 4; ++k) {
        const int idx = (k * 64 + lane) * 4;
        L0[k] = *(const float4*)(leT + 0 * H + idx);
        L1[k] = *(const float4*)(leT + 1 * H + idx);
        L2[k] = *(const float4*)(leT + 2 * H + idx);
    }

    float4 acc[4];
    #pragma unroll
    for (int k = 0; k < 4; ++k) acc[k] = make_float4(0.f, 0.f, 0.f, 0.f);
    float m = -INFINITY, Z = 0.f;

    for (int i = 0; i < RPW; ++i) {
        const int row = b * S + s0 + i;
        const float* r = df + (size_t)row * H;
        float4 d[4];
        #pragma unroll
        for (int k = 0; k < 4; ++k)
            d[k] = *(const float4*)(r + (k * 64 + lane) * 4);

        float ssq = 0.f, d0 = 0.f, d1 = 0.f, d2 = 0.f;
        #pragma unroll
        for (int k = 0; k < 4; ++k) {
            ssq += d[k].x * d[k].x   + d[k].y * d[k].y   + d[k].z * d[k].z   + d[k].w * d[k].w;
            d0  += d[k].x * L0[k].x  + d[k].y * L0[k].y  + d[k].z * L0[k].z  + d[k].w * L0[k].w;
            d1  += d[k].x * L1[k].x  + d[k].y * L1[k].y  + d[k].z * L1[k].z  + d[k].w * L1[k].w;
            d2  += d[k].x * L2[k].x  + d[k].y * L2[k].y  + d[k].z * L2[k].z  + d[k].w * L2[k].w;
        }
        #pragma unroll
        for (int off = 32; off > 0; off >>= 1) {
            ssq += __shfl_xor(ssq, off);
            d0  += __shfl_xor(d0, off);
            d1  += __shfl_xor(d1, off);
            d2  += __shfl_xor(d2, off);
        }

        const float rnrm = 1.0f / fmaxf(sqrtf(ssq), NEPS);
        const float bias = 10000.0f * (mask[row] - 1.0f);
        const float v0 = d0 * rnrm + bias;
        const float v1 = d1 * rnrm + bias;
        const float v2 = d2 * rnrm + bias;
        const float p  = fmaxf(fmaxf(v0, v1), v2);
        if (lane == 0) {
            float* o = atten + (size_t)row * L;
            o[0] = v0; o[1] = v1; o[2] = v2;
            pooled[row] = p;
        }

        // online softmax accumulate (p is wave-uniform -> no divergence)
        if (p > m) {
            const float sc = __expf(m - p);   // exp(-inf)=0 on first row
            Z *= sc;
            #pragma unroll
            for (int k = 0; k < 4; ++k) {
                acc[k].x *= sc; acc[k].y *= sc; acc[k].z *= sc; acc[k].w *= sc;
            }
            m = p;
        }
        const float e = __expf(p - m);
        Z += e;
        #pragma unroll
        for (int k = 0; k < 4; ++k) {
            acc[k].x += e * d[k].x;
            acc[k].y += e * d[k].y;
            acc[k].z += e * d[k].z;
            acc[k].w += e * d[k].w;
        }
    }

    float* ap = accp + ((size_t)b * WPB + j) * H;
    #pragma unroll
    for (int k = 0; k < 4; ++k)
        *(float4*)(ap + (k * 64 + lane) * 4) = acc[k];
    if (lane == 0) {
        mz[((size_t)b * WPB + j) * 2 + 0] = m;
        mz[((size_t)b * WPB + j) * 2 + 1] = Z;
    }
}

// ---------------------------------------------------------------------------
// Kernel 3 (epilogue): per batch b — combine the 64 wave partials:
//   M = max_j m_j,  Zt = sum_j Z_j e^(m_j - M)
//   fa[b][h]   = (sum_j accp[b][j][h] e^(m_j - M)) / Zt
//   norm[b][s] = e^(pooled[b][s] - M) / Zt
// ---------------------------------------------------------------------------
__global__ __launch_bounds__(256) void epilogue(const float* __restrict__ accp,
                                                const float* __restrict__ mz,
                                                const float* __restrict__ pooled,
                                                float* __restrict__ norm,
                                                float* __restrict__ fa) {
    const int b = blockIdx.x;
    const int tid = threadIdx.x;

    __shared__ float sM, sZ;
    __shared__ float ew[WPB];

    float mj = 0.f, zj = 0.f;
    if (tid < WPB) {
        const float2 p = *(const float2*)(mz + ((size_t)b * WPB + tid) * 2);
        mj = p.x; zj = p.y;
        float M = wave_reduce_max(mj);
        if (tid == 0) sM = M;
    }
    __syncthreads();
    const float M = sM;
    if (tid < WPB) {
        const float e = __expf(mj - M);
        ew[tid] = e;
        float z = wave_reduce_sum(zj * e);
        if (tid == 0) sZ = z;
    }
    __syncthreads();
    const float rZ = 1.0f / sZ;

    // fa: each thread owns 4 consecutive h
    const float* ap = accp + (size_t)b * WPB * H + tid * 4;
    float4 a = make_float4(0.f, 0.f, 0.f, 0.f);
    #pragma unroll 8
    for (int j = 0; j < WPB; ++j) {
        const float4 v = *(const float4*)(ap + (size_t)j * H);
        const float w = ew[j];
        a.x += w * v.x; a.y += w * v.y; a.z += w * v.z; a.w += w * v.w;
    }
    a.x *= rZ; a.y *= rZ; a.z *= rZ; a.w *= rZ;
    *(float4*)(fa + (size_t)b * H + tid * 4) = a;

    // normalized: each thread owns 4 consecutive s
    const float4 p4 = *(const float4*)(pooled + (size_t)b * S + tid * 4);
    float4 n4;
    n4.x = __expf(p4.x - M) * rZ;
    n4.y = __expf(p4.y - M) * rZ;
    n4.z = __expf(p4.z - M) * rZ;
    n4.w = __expf(p4.w - M) * rZ;
    *(float4*)(norm + (size_t)b * S + tid * 4) = n4;
}

// ---------------------------------------------------------------------------
extern "C" void kernel_launch(void* const* d_in, const int* in_sizes, int n_in,
                              void* d_out, int out_size, void* d_ws, size_t ws_size,
                              hipStream_t stream) {
    const float* df   = (const float*)d_in[0];  // [B,S,H]
    const float* le   = (const float*)d_in[1];  // [H,L]
    const float* mask = (const float*)d_in[2];  // [B,S]

    float* out   = (float*)d_out;
    float* fa    = out;                          // [B,H]        65536
    float* atten = out + (size_t)B * H;          // [B,S,L]      196608
    float* norm  = atten + (size_t)B * S * L;    // [B,1,S]      65536

    float* leT    = (float*)d_ws;                // [L,H]            12288 f
    float* pooled = leT + (size_t)L * H;         // [B,S]            65536 f
    float* mz     = pooled + (size_t)B * S;      // [B,WPB,2]         8192 f
    float* accp   = mz + (size_t)B * WPB * 2;    // [B,WPB,H]      4194304 f

    norm_labels<<<1, 256, 0, stream>>>(le, leT);
    fused_stream<<<(B * WPB) / 4, 256, 0, stream>>>(df, leT, mask, atten, pooled, accp, mz);
    epilogue<<<B, 256, 0, stream>>>(accp, mz, pooled, norm, fa);
}